// Round 1
// baseline (119.888 us; speedup 1.0000x reference)
//
#include <hip/hip_runtime.h>

// HMM forward, B=8192, TMAX=2048, N=2 states, obs in {0,1}.
// One wave (64 lanes) per sequence; ordered 2x2 matrix-product reduction.
#define TMAX_C 2048
#define ROWLEN (TMAX_C + 1)

__global__ __launch_bounds__(256, 8) void hmm_fwd_kernel(
    const int* __restrict__ combined,   // (B, TMAX+1): x[0..TMAX-1], T at [TMAX]
    const float* __restrict__ sp,       // (2,)  state prior logits
    const float* __restrict__ tr,       // (2,2) transition logits
    const float* __restrict__ emi,      // (2,2) emission logits
    float* __restrict__ out, int B)
{
    const int lane = threadIdx.x & 63;
    const int wave_in_block = threadIdx.x >> 6;
    const int b = blockIdx.x * (blockDim.x >> 6) + wave_in_block;
    if (b >= B) return;

    // ---- tiny softmaxes, computed redundantly per lane (cheap) ----
    float p0 = __expf(sp[0]), p1 = __expf(sp[1]);
    { float s = p0 + p1; p0 /= s; p1 /= s; }

    float A00, A01, A10, A11;
    { float e0 = __expf(tr[0]), e1 = __expf(tr[1]); float s = e0 + e1; A00 = e0/s; A01 = e1/s; }
    { float e0 = __expf(tr[2]), e1 = __expf(tr[3]); float s = e0 + e1; A10 = e0/s; A11 = e1/s; }

    float em00, em01, em10, em11;   // em[state][obs]
    { float e0 = __expf(emi[0]), e1 = __expf(emi[1]); float s = e0 + e1; em00 = e0/s; em01 = e1/s; }
    { float e0 = __expf(emi[2]), e1 = __expf(emi[3]); float s = e0 + e1; em10 = e0/s; em11 = e1/s; }

    // M_o[i][j] = A[i][j] * em[j][o]
    const float M0_00 = A00*em00, M0_01 = A01*em10, M0_10 = A10*em00, M0_11 = A11*em10;
    const float M1_00 = A00*em01, M1_01 = A01*em11, M1_10 = A10*em01, M1_11 = A11*em11;

    const int* __restrict__ row = combined + (size_t)b * ROWLEN;
    const int T = row[TMAX_C];
    const int steps = T - 1;                 // matrices applied at t = 1 .. T-1
    const int chunk = (steps + 63) >> 6;     // per-lane contiguous chunk length

    // ---- per-lane ordered product over its chunk ----
    float P00 = 1.f, P01 = 0.f, P10 = 0.f, P11 = 1.f;
    const int start = 1 + lane * chunk;
    const int end   = min(start + chunk, T);
    for (int t = start; t < end; ++t) {
        const int xt = row[t];
        const float m00 = xt ? M1_00 : M0_00;
        const float m01 = xt ? M1_01 : M0_01;
        const float m10 = xt ? M1_10 : M0_10;
        const float m11 = xt ? M1_11 : M0_11;
        const float n00 = P00*m00 + P01*m10;
        const float n01 = P00*m01 + P01*m11;
        const float n10 = P10*m00 + P11*m10;
        const float n11 = P10*m01 + P11*m11;
        P00 = n00; P01 = n01; P10 = n10; P11 = n11;
    }

    // ---- ordered log-tree reduction across 64 lanes ----
    // Invariant: after round with offset `off`, lane i holds product over
    // chunks [i, min(i + 2*off, 64)).
    #pragma unroll
    for (int off = 1; off < 64; off <<= 1) {
        const float q00 = __shfl_down(P00, off);
        const float q01 = __shfl_down(P01, off);
        const float q10 = __shfl_down(P10, off);
        const float q11 = __shfl_down(P11, off);
        if (lane + off < 64) {
            const float n00 = P00*q00 + P01*q10;
            const float n01 = P00*q01 + P01*q11;
            const float n10 = P10*q00 + P11*q10;
            const float n11 = P10*q01 + P11*q11;
            P00 = n00; P01 = n01; P10 = n10; P11 = n11;
        }
    }

    if (lane == 0) {
        const int x0 = row[0];
        // alpha0[j] = em[j][x0] * priors[j]
        const float a0 = (x0 ? em01 : em00) * p0;
        const float a1 = (x0 ? em11 : em10) * p1;
        const float v0 = a0*P00 + a1*P10;
        const float v1 = a0*P01 + a1*P11;
        out[b] = v0 + v1;
    }
}

extern "C" void kernel_launch(void* const* d_in, const int* in_sizes, int n_in,
                              void* d_out, int out_size, void* d_ws, size_t ws_size,
                              hipStream_t stream) {
    const int*   combined = (const int*)d_in[0];
    const float* sp       = (const float*)d_in[1];
    const float* tr       = (const float*)d_in[2];
    const float* emi      = (const float*)d_in[3];
    float* out = (float*)d_out;

    const int B = out_size;                 // 8192 sequences, one output each
    const int waves_per_block = 4;          // 256 threads
    const int grid = (B + waves_per_block - 1) / waves_per_block;
    hmm_fwd_kernel<<<grid, 256, 0, stream>>>(combined, sp, tr, emi, out, B);
}

// Round 3
// 102.818 us; speedup vs baseline: 1.1660x; 1.1660x over previous
//
#include <hip/hip_runtime.h>

// HMM forward, B=8192, TMAX=2048, N=2 states, obs in {0,1}.
// One wave (64 lanes) per sequence. Phase 1: wave loads obs in coalesced
// 64-wide rows. Phase 2: __ballot packs each row into a 64-bit mask; lane L
// keeps the bits of its own contiguous 32-obs chunk (register transpose).
// Phase 3: fully-unrolled 32-step 2x2 matrix chain (bit-selected M0/M1,
// predicated on per-lane valid count). Ordered shuffle-tree combine.
// NO LDS, NO __syncthreads (R2's LDS-table version failed post-timing
// validation; this keeps the R1 skeleton that passed all tripwires).
#define TMAX_C 2048
#define ROWLEN (TMAX_C + 1)

__global__ __launch_bounds__(256, 8) void hmm_fwd_kernel(
    const int* __restrict__ combined,   // (B, TMAX+1): x[0..TMAX-1], T at [TMAX]
    const float* __restrict__ sp,       // (2,)  state prior logits
    const float* __restrict__ tr,       // (2,2) transition logits
    const float* __restrict__ emi,      // (2,2) emission logits
    float* __restrict__ out, int B)
{
    const int lane = threadIdx.x & 63;
    const int b = blockIdx.x * (blockDim.x >> 6) + (threadIdx.x >> 6);
    if (b >= B) return;

    // ---- tiny softmaxes, computed redundantly per lane (cheap) ----
    float p0 = __expf(sp[0]), p1 = __expf(sp[1]);
    { float s = p0 + p1; p0 /= s; p1 /= s; }

    float A00, A01, A10, A11;
    { float e0 = __expf(tr[0]), e1 = __expf(tr[1]); float s = e0 + e1; A00 = e0/s; A01 = e1/s; }
    { float e0 = __expf(tr[2]), e1 = __expf(tr[3]); float s = e0 + e1; A10 = e0/s; A11 = e1/s; }

    float em00, em01, em10, em11;   // em[state][obs]
    { float e0 = __expf(emi[0]), e1 = __expf(emi[1]); float s = e0 + e1; em00 = e0/s; em01 = e1/s; }
    { float e0 = __expf(emi[2]), e1 = __expf(emi[3]); float s = e0 + e1; em10 = e0/s; em11 = e1/s; }

    // M_o[i][j] = A[i][j] * em[j][o]   (row-vector convention: alpha_new = alpha * M)
    const float M0_00 = A00*em00, M0_01 = A01*em10, M0_10 = A10*em00, M0_11 = A11*em10;
    const float M1_00 = A00*em01, M1_01 = A01*em11, M1_10 = A10*em01, M1_11 = A11*em11;

    const int* __restrict__ row = combined + (size_t)b * ROWLEN;
    const int T = row[TMAX_C];
    const int steps = T - 1;                 // matrices applied at t = 1 .. T-1
    const int nwords = (steps + 63) >> 6;    // 64-obs words needed (0..32)
    const int my_word = lane >> 1;           // lane's chunk = bits [32*lane, 32*lane+32)

    // ---- phases 1+2: batched coalesced loads + ballot transpose ----
    unsigned long long my_mask = 0ULL;
    #pragma unroll
    for (int g = 0; g < 4; ++g) {
        if ((g << 3) < nwords) {             // wave-uniform group guard
            int a[8];
            #pragma unroll
            for (int u = 0; u < 8; ++u) {
                // max t = 1 + 31*64 + 63 = 2048: always in-bounds (T column).
                // Bits past `steps` are garbage but provably dead (cnt mask).
                a[u] = row[1 + (((g << 3) + u) << 6) + lane];
            }
            #pragma unroll
            for (int u = 0; u < 8; ++u) {
                const unsigned long long m = __ballot(a[u] != 0);
                if (((g << 3) + u) == my_word) my_mask = m;
            }
        }
    }
    const unsigned int bits = (lane & 1) ? (unsigned int)(my_mask >> 32)
                                         : (unsigned int)my_mask;
    const int cnt = min(max(steps - (lane << 5), 0), 32);  // valid obs this lane

    // ---- phase 3: fully-unrolled 32-step 2x2 product chain ----
    float P00 = 1.f, P01 = 0.f, P10 = 0.f, P11 = 1.f;
    #pragma unroll
    for (int j = 0; j < 32; ++j) {
        const bool bit = (bits >> j) & 1u;
        const float m00 = bit ? M1_00 : M0_00;
        const float m01 = bit ? M1_01 : M0_01;
        const float m10 = bit ? M1_10 : M0_10;
        const float m11 = bit ? M1_11 : M0_11;
        const float n00 = P00*m00 + P01*m10;
        const float n01 = P00*m01 + P01*m11;
        const float n10 = P10*m00 + P11*m10;
        const float n11 = P10*m01 + P11*m11;
        const bool ok = j < cnt;
        P00 = ok ? n00 : P00;
        P01 = ok ? n01 : P01;
        P10 = ok ? n10 : P10;
        P11 = ok ? n11 : P11;
    }

    // ---- ordered log-tree reduction across 64 lanes ----
    #pragma unroll
    for (int off = 1; off < 64; off <<= 1) {
        const float q00 = __shfl_down(P00, off);
        const float q01 = __shfl_down(P01, off);
        const float q10 = __shfl_down(P10, off);
        const float q11 = __shfl_down(P11, off);
        if (lane + off < 64) {
            const float n00 = P00*q00 + P01*q10;
            const float n01 = P00*q01 + P01*q11;
            const float n10 = P10*q00 + P11*q10;
            const float n11 = P10*q01 + P11*q11;
            P00 = n00; P01 = n01; P10 = n10; P11 = n11;
        }
    }

    if (lane == 0) {
        const int x0 = row[0];
        // alpha0[j] = em[j][x0] * priors[j]
        const float a0 = (x0 ? em01 : em00) * p0;
        const float a1 = (x0 ? em11 : em10) * p1;
        const float v0 = a0*P00 + a1*P10;
        const float v1 = a0*P01 + a1*P11;
        out[b] = v0 + v1;
    }
}

extern "C" void kernel_launch(void* const* d_in, const int* in_sizes, int n_in,
                              void* d_out, int out_size, void* d_ws, size_t ws_size,
                              hipStream_t stream) {
    const int*   combined = (const int*)d_in[0];
    const float* sp       = (const float*)d_in[1];
    const float* tr       = (const float*)d_in[2];
    const float* emi      = (const float*)d_in[3];
    float* out = (float*)d_out;

    const int B = out_size;                 // 8192 sequences, one output each
    const int waves_per_block = 4;          // 256 threads
    const int grid = (B + waves_per_block - 1) / waves_per_block;
    hmm_fwd_kernel<<<grid, 256, 0, stream>>>(combined, sp, tr, emi, out, B);
}

// Round 4
// 102.247 us; speedup vs baseline: 1.1725x; 1.0056x over previous
//
#include <hip/hip_runtime.h>

// HMM forward, B=8192, TMAX=2048, N=2 states, obs in {0,1}.
// One wave (64 lanes) per sequence.
//   Phase 1: ALL coalesced 64-wide row loads issued up-front (guarded by
//            wave-uniform group tests, no dependent ops between bursts).
//   Phase 2: __ballot packs each 64-obs row into a 64-bit mask; lane L keeps
//            the 32-bit half covering its own contiguous chunk.
//   Phase 3: fully-unrolled 32-step 2x2 matrix chain, predicated on cnt.
//   Phase 4: ordered shuffle-tree combine; lane 0 applies alpha0, writes out.
// NO LDS, NO __syncthreads (R2's LDS version failed post-timing validation).
#define TMAX_C 2048
#define ROWLEN (TMAX_C + 1)

__global__ __launch_bounds__(256, 8) void hmm_fwd_kernel(
    const int* __restrict__ combined,   // (B, TMAX+1): x[0..TMAX-1], T at [TMAX]
    const float* __restrict__ sp,       // (2,)  state prior logits
    const float* __restrict__ tr,       // (2,2) transition logits
    const float* __restrict__ emi,      // (2,2) emission logits
    float* __restrict__ out, int B)
{
    const int lane = threadIdx.x & 63;
    const int b = blockIdx.x * (blockDim.x >> 6) + (threadIdx.x >> 6);
    if (b >= B) return;

    const int* __restrict__ row = combined + (size_t)b * ROWLEN;
    const int T = row[TMAX_C];               // gates everything; issue first
    const int steps = T - 1;                 // matrices applied at t = 1 .. T-1
    const int nwords = (steps + 63) >> 6;    // 64-obs words needed (0..32)

    // ---- phase 1: all loads up-front, no dependent ops between bursts ----
    // All addresses <= 2048 are in-bounds for any T; guards only save BW.
    int a[32];
    #pragma unroll
    for (int g = 0; g < 4; ++g) {
        if ((g << 3) < nwords) {
            #pragma unroll
            for (int u = 0; u < 8; ++u) {
                a[(g << 3) + u] = row[1 + ((((g << 3) + u)) << 6) + lane];
            }
        }
    }

    // ---- tiny softmaxes (overlap with outstanding loads) ----
    float p0 = __expf(sp[0]), p1 = __expf(sp[1]);
    { float s = p0 + p1; p0 /= s; p1 /= s; }
    float A00, A01, A10, A11;
    { float e0 = __expf(tr[0]), e1 = __expf(tr[1]); float s = e0 + e1; A00 = e0/s; A01 = e1/s; }
    { float e0 = __expf(tr[2]), e1 = __expf(tr[3]); float s = e0 + e1; A10 = e0/s; A11 = e1/s; }
    float em00, em01, em10, em11;   // em[state][obs]
    { float e0 = __expf(emi[0]), e1 = __expf(emi[1]); float s = e0 + e1; em00 = e0/s; em01 = e1/s; }
    { float e0 = __expf(emi[2]), e1 = __expf(emi[3]); float s = e0 + e1; em10 = e0/s; em11 = e1/s; }

    // M_o[i][j] = A[i][j] * em[j][o]   (row-vector convention)
    const float M0_00 = A00*em00, M0_01 = A01*em10, M0_10 = A10*em00, M0_11 = A11*em10;
    const float M1_00 = A00*em01, M1_01 = A01*em11, M1_10 = A10*em01, M1_11 = A11*em11;

    // ---- phase 2: ballot transpose ----
    const int my_word = lane >> 1;           // lane's chunk = bits [32*lane, 32*lane+32)
    unsigned long long my_mask = 0ULL;
    #pragma unroll
    for (int g = 0; g < 4; ++g) {
        if ((g << 3) < nwords) {
            #pragma unroll
            for (int u = 0; u < 8; ++u) {
                const int w = (g << 3) + u;
                const unsigned long long m = __ballot(a[w] != 0);
                if (w == my_word) my_mask = m;
            }
        }
    }
    const unsigned int bits = (lane & 1) ? (unsigned int)(my_mask >> 32)
                                         : (unsigned int)my_mask;
    const int cnt = min(max(steps - (lane << 5), 0), 32);  // valid obs this lane

    // ---- phase 3: fully-unrolled 32-step 2x2 product chain ----
    float P00 = 1.f, P01 = 0.f, P10 = 0.f, P11 = 1.f;
    #pragma unroll
    for (int j = 0; j < 32; ++j) {
        const bool bit = (bits >> j) & 1u;
        const float m00 = bit ? M1_00 : M0_00;
        const float m01 = bit ? M1_01 : M0_01;
        const float m10 = bit ? M1_10 : M0_10;
        const float m11 = bit ? M1_11 : M0_11;
        const float n00 = P00*m00 + P01*m10;
        const float n01 = P00*m01 + P01*m11;
        const float n10 = P10*m00 + P11*m10;
        const float n11 = P10*m01 + P11*m11;
        const bool ok = j < cnt;
        P00 = ok ? n00 : P00;
        P01 = ok ? n01 : P01;
        P10 = ok ? n10 : P10;
        P11 = ok ? n11 : P11;
    }

    // ---- phase 4: ordered log-tree reduction across 64 lanes ----
    #pragma unroll
    for (int off = 1; off < 64; off <<= 1) {
        const float q00 = __shfl_down(P00, off);
        const float q01 = __shfl_down(P01, off);
        const float q10 = __shfl_down(P10, off);
        const float q11 = __shfl_down(P11, off);
        if (lane + off < 64) {
            const float n00 = P00*q00 + P01*q10;
            const float n01 = P00*q01 + P01*q11;
            const float n10 = P10*q00 + P11*q10;
            const float n11 = P10*q01 + P11*q11;
            P00 = n00; P01 = n01; P10 = n10; P11 = n11;
        }
    }

    if (lane == 0) {
        const int x0 = row[0];
        // alpha0[j] = em[j][x0] * priors[j]
        const float a0 = (x0 ? em01 : em00) * p0;
        const float a1 = (x0 ? em11 : em10) * p1;
        const float v0 = a0*P00 + a1*P10;
        const float v1 = a0*P01 + a1*P11;
        out[b] = v0 + v1;
    }
}

extern "C" void kernel_launch(void* const* d_in, const int* in_sizes, int n_in,
                              void* d_out, int out_size, void* d_ws, size_t ws_size,
                              hipStream_t stream) {
    const int*   combined = (const int*)d_in[0];
    const float* sp       = (const float*)d_in[1];
    const float* tr       = (const float*)d_in[2];
    const float* emi      = (const float*)d_in[3];
    float* out = (float*)d_out;

    const int B = out_size;                 // 8192 sequences, one output each
    const int waves_per_block = 4;          // 256 threads
    const int grid = (B + waves_per_block - 1) / waves_per_block;
    hmm_fwd_kernel<<<grid, 256, 0, stream>>>(combined, sp, tr, emi, out, B);
}